// Round 6
// baseline (201.114 us; speedup 1.0000x reference)
//
#include <hip/hip_runtime.h>
#include <hip/hip_bf16.h>
#include <math.h>

typedef __bf16 bf16x8 __attribute__((ext_vector_type(8)));
typedef float floatx4 __attribute__((ext_vector_type(4)));

#define DK    1536   // inner dim D
#define MROWS 4096   // B*L
#define NOUT  1536   // first GEMM output dim
#define OUTC  23     // second GEMM output dim
#define AFF_SZ (MROWS * 12)

// ws layout (bytes): Hb @0 (12.58MB) | w1b @12582912 (4.72MB) | Wp @17301504
// (96KB, 32x1536 bf16) | c12 @17399808 (64 floats: c1[32], c2[32])
#define W1B_OFF 12582912
#define WP_OFF  17301504
#define C_OFF   17399808

__device__ __forceinline__ unsigned int pkbf(float lo, float hi) {
    unsigned int a = __float_as_uint(lo) + 0x8000u;
    unsigned int b = __float_as_uint(hi) + 0x8000u;
    return (b & 0xffff0000u) | (a >> 16);
}
__device__ __forceinline__ unsigned short f2bf1(float v) {
    return (unsigned short)((__float_as_uint(v) + 0x8000u) >> 16);
}
__device__ __forceinline__ float bflo(unsigned int u) { return __uint_as_float(u << 16); }
__device__ __forceinline__ float bfhi(unsigned int u) { return __uint_as_float(u & 0xffff0000u); }

// ---------------------------------------------------------------------------
// Setup: w1 -> bf16; W' = (ln_g (.) w2) -> bf16 padded to 32 rows;
//        c1[o] = sum g*w2[o], c2[o] = sum lnb*w2[o].
// ---------------------------------------------------------------------------
__global__ __launch_bounds__(256)
void setup_kernel(const float* __restrict__ w1, const float* __restrict__ ln_g,
                  const float* __restrict__ ln_b, const float* __restrict__ w2,
                  unsigned short* __restrict__ w1b, unsigned short* __restrict__ wpb,
                  float* __restrict__ c12)
{
    const int b = blockIdx.x, tid = threadIdx.x;
    if (b < 1152) {                       // w1 convert: 1536*1536 = 1152*2048
        const int base = b * 2048 + tid * 8;
        float4 a = *(const float4*)(w1 + base);
        float4 c = *(const float4*)(w1 + base + 4);
        uint4 u;
        u.x = pkbf(a.x, a.y); u.y = pkbf(a.z, a.w);
        u.z = pkbf(c.x, c.y); u.w = pkbf(c.z, c.w);
        *(uint4*)(w1b + base) = u;
    } else if (b < 1176) {                // W': 32*1536 = 24*2048
        const int base = (b - 1152) * 2048 + tid * 8;
        const int o = base / DK;
        const int d = base - o * DK;
        uint4 u = make_uint4(0, 0, 0, 0);
        if (o < OUTC) {
            float4 a  = *(const float4*)(w2 + (size_t)o * DK + d);
            float4 c  = *(const float4*)(w2 + (size_t)o * DK + d + 4);
            float4 g0 = *(const float4*)(ln_g + d);
            float4 g1 = *(const float4*)(ln_g + d + 4);
            u.x = pkbf(a.x * g0.x, a.y * g0.y);
            u.y = pkbf(a.z * g0.z, a.w * g0.w);
            u.z = pkbf(c.x * g1.x, c.y * g1.y);
            u.w = pkbf(c.z * g1.z, c.w * g1.w);
        }
        *(uint4*)(wpb + base) = u;
    } else {                              // c1/c2: one block per o
        const int o = b - 1176;
        float s1 = 0.f, s2 = 0.f;
        for (int d = tid; d < DK; d += 256) {
            float w = w2[(size_t)o * DK + d];
            s1 += ln_g[d] * w;
            s2 += ln_b[d] * w;
        }
        __shared__ float r1[4], r2[4];
        const int lane = tid & 63, wave = tid >> 6;
        #pragma unroll
        for (int off = 32; off > 0; off >>= 1) {
            s1 += __shfl_down(s1, off, 64);
            s2 += __shfl_down(s2, off, 64);
        }
        if (lane == 0) { r1[wave] = s1; r2[wave] = s2; }
        __syncthreads();
        if (tid == 0) {
            c12[o]      = r1[0] + r1[1] + r1[2] + r1[3];
            c12[32 + o] = r2[0] + r2[1] + r2[2] + r2[3];
        }
    }
}

// ---------------------------------------------------------------------------
// Kernel 1: Hb = bf16( gelu(x @ w1b^T + b1) )  [M=4096, N=1536, K=1536]
// BM=64, BN=128, BK=64 -> 768 blocks = 3/CU. 4 waves (2x2), wave 32x64.
// Register prefetch of next k-tile; last iteration peeled (no in-loop branch).
// NO min-waves clamp: round 5 showed __launch_bounds__(256,4) caps VGPR at 56
// -> prefetch regs spill to scratch -> ~88 MB extra HBM writes. 84-110 VGPRs
// with no spill is the right trade here.
// ---------------------------------------------------------------------------
__global__ __launch_bounds__(256)
void gemm1_kernel(const float* __restrict__ A, const unsigned short* __restrict__ Bw,
                  const float* __restrict__ b1, unsigned short* __restrict__ Hb)
{
    __shared__ __align__(16) unsigned short As[64][72];
    __shared__ __align__(16) unsigned short Bs[128][72];

    const int tid    = threadIdx.x;
    const int wave   = tid >> 6;
    const int lane   = tid & 63;
    const int wm     = (wave & 1) * 32;
    const int wn     = (wave >> 1) * 64;
    const int lane15 = lane & 15;
    const int quad   = lane >> 4;

    const int row0 = blockIdx.x * 64;
    const int col0 = blockIdx.y * 128;

    const int arow = tid >> 4;            // 0..15, +16*i
    const int ac4  = (tid & 15) << 2;     // 0..60 step 4
    const int brow = tid >> 3;            // 0..31, +32*i
    const int b8   = (tid & 7) << 3;      // 0..56 step 8

    const float*          Ap = A  + (size_t)(row0 + arow) * DK + ac4;
    const unsigned short* Bp = Bw + (size_t)(col0 + brow) * DK + b8;

    floatx4 acc[2][4] = {};
    float4 pa[4];
    uint4  pb[4];

    #pragma unroll
    for (int i = 0; i < 4; ++i) pa[i] = *(const float4*)(Ap + (size_t)(16 * i) * DK);
    #pragma unroll
    for (int i = 0; i < 4; ++i) pb[i] = *(const uint4*)(Bp + (size_t)(32 * i) * DK);

    #define STAGE_TILE()                                                        \
        do {                                                                    \
            _Pragma("unroll")                                                   \
            for (int i = 0; i < 4; ++i) {                                       \
                uint2 u = make_uint2(pkbf(pa[i].x, pa[i].y),                    \
                                     pkbf(pa[i].z, pa[i].w));                   \
                *(uint2*)(&As[arow + 16 * i][ac4]) = u;                         \
            }                                                                   \
            _Pragma("unroll")                                                   \
            for (int i = 0; i < 4; ++i)                                         \
                *(uint4*)(&Bs[brow + 32 * i][b8]) = pb[i];                      \
        } while (0)

    #define MFMA_TILE()                                                         \
        do {                                                                    \
            _Pragma("unroll")                                                   \
            for (int ks = 0; ks < 2; ++ks) {                                    \
                bf16x8 af[2], bfr[4];                                           \
                _Pragma("unroll")                                               \
                for (int mt = 0; mt < 2; ++mt)                                  \
                    af[mt] = *(const bf16x8*)(&As[wm + mt * 16 + lane15]        \
                                                [ks * 32 + quad * 8]);          \
                _Pragma("unroll")                                               \
                for (int nt = 0; nt < 4; ++nt)                                  \
                    bfr[nt] = *(const bf16x8*)(&Bs[wn + nt * 16 + lane15]       \
                                                 [ks * 32 + quad * 8]);         \
                _Pragma("unroll")                                               \
                for (int mt = 0; mt < 2; ++mt)                                  \
                    _Pragma("unroll")                                           \
                    for (int nt = 0; nt < 4; ++nt)                              \
                        acc[mt][nt] = __builtin_amdgcn_mfma_f32_16x16x32_bf16(  \
                            af[mt], bfr[nt], acc[mt][nt], 0, 0, 0);             \
            }                                                                   \
        } while (0)

    for (int k0 = 0; k0 < DK - 64; k0 += 64) {
        STAGE_TILE();
        #pragma unroll
        for (int i = 0; i < 4; ++i)
            pa[i] = *(const float4*)(Ap + (size_t)(16 * i) * DK + k0 + 64);
        #pragma unroll
        for (int i = 0; i < 4; ++i)
            pb[i] = *(const uint4*)(Bp + (size_t)(32 * i) * DK + k0 + 64);
        __syncthreads();
        MFMA_TILE();
        __syncthreads();
    }
    // peeled last tile: no prefetch
    STAGE_TILE();
    __syncthreads();
    MFMA_TILE();

    #pragma unroll
    for (int mt = 0; mt < 2; ++mt)
        #pragma unroll
        for (int nt = 0; nt < 4; ++nt)
            #pragma unroll
            for (int r = 0; r < 4; ++r) {
                int row = row0 + wm + mt * 16 + quad * 4 + r;
                int col = col0 + wn + nt * 16 + lane15;
                float v = acc[mt][nt][r] + b1[col];
                v = 0.5f * v * (1.0f + erff(v * 0.70710678118654752f));
                Hb[(size_t)row * NOUT + col] = f2bf1(v);
            }
}

// ---------------------------------------------------------------------------
// Kernel 2: head. 8 rows/block (512 blocks).
// P1: load bf16 h -> LDS + LN stats. LN folded: p = rstd*(S - mu*c1) + c2 + b2,
//     S = h @ (g.*w2)^T.  P2: S via MFMA, K split 4 ways.  P3: finish + geometry.
// ---------------------------------------------------------------------------
__global__ __launch_bounds__(256)
void head_kernel(const unsigned short* __restrict__ Hb, const unsigned short* __restrict__ Wp,
                 const float* __restrict__ c12, const float* __restrict__ b2,
                 const float* __restrict__ affine, const int* __restrict__ amask,
                 float* __restrict__ out)
{
    __shared__ __align__(16) unsigned short hb[8][DK];
    __shared__ float st[8][2];
    __shared__ float pred[4][16][32];
    __shared__ float pr[8][32];

    const int tid    = threadIdx.x;
    const int lane   = tid & 63;
    const int wave   = tid >> 6;
    const int lane15 = lane & 15;
    const int quad   = lane >> 4;
    const int row8   = blockIdx.x * 8;

    // -------- P1: load 2 rows per wave + stats --------
    #pragma unroll
    for (int rr = 0; rr < 2; ++rr) {
        const int r = wave * 2 + rr;
        const unsigned short* src = Hb + (size_t)(row8 + r) * DK;
        float s = 0.f, ss = 0.f;
        #pragma unroll
        for (int j = 0; j < 3; ++j) {
            const int e8 = lane + 64 * j;
            uint4 u = *(const uint4*)(src + e8 * 8);
            *(uint4*)(&hb[r][e8 * 8]) = u;
            float f0 = bflo(u.x), f1 = bfhi(u.x), f2 = bflo(u.y), f3 = bfhi(u.y);
            float f4 = bflo(u.z), f5 = bfhi(u.z), f6 = bflo(u.w), f7 = bfhi(u.w);
            s  += ((f0 + f1) + (f2 + f3)) + ((f4 + f5) + (f6 + f7));
            ss += ((f0*f0 + f1*f1) + (f2*f2 + f3*f3)) + ((f4*f4 + f5*f5) + (f6*f6 + f7*f7));
        }
        #pragma unroll
        for (int off = 32; off > 0; off >>= 1) {
            s  += __shfl_down(s, off, 64);
            ss += __shfl_down(ss, off, 64);
        }
        if (lane == 0) {
            float mu  = s * (1.f / DK);
            float var = ss * (1.f / DK) - mu * mu;
            st[r][0] = mu;
            st[r][1] = 1.f / sqrtf(var + 1e-5f);
        }
    }
    __syncthreads();

    // -------- P2: S = h @ W'^T, wave = k-quarter --------
    {
        const int mrow = lane15 & 7;
        const unsigned short* w0  = Wp + (size_t)lane15 * DK;
        const unsigned short* w1r = Wp + (size_t)(16 + lane15) * DK;
        floatx4 a0 = {0.f, 0.f, 0.f, 0.f}, a1 = {0.f, 0.f, 0.f, 0.f};
        #pragma unroll
        for (int kk = 0; kk < 12; ++kk) {
            const int kb = wave * 384 + kk * 32 + quad * 8;
            bf16x8 afr = *(const bf16x8*)(&hb[mrow][kb]);
            bf16x8 bf0 = *(const bf16x8*)(w0 + kb);
            bf16x8 bf1 = *(const bf16x8*)(w1r + kb);
            a0 = __builtin_amdgcn_mfma_f32_16x16x32_bf16(afr, bf0, a0, 0, 0, 0);
            a1 = __builtin_amdgcn_mfma_f32_16x16x32_bf16(afr, bf1, a1, 0, 0, 0);
        }
        #pragma unroll
        for (int r2 = 0; r2 < 4; ++r2) {
            pred[wave][quad * 4 + r2][lane15]      = a0[r2];
            pred[wave][quad * 4 + r2][16 + lane15] = a1[r2];
        }
    }
    __syncthreads();

    // -------- P3a: finish p --------
    {
        const int row = tid >> 5;
        const int o   = tid & 31;
        if (o < OUTC) {
            float S = pred[0][row][o] + pred[1][row][o] + pred[2][row][o] + pred[3][row][o];
            float mu = st[row][0], rstd = st[row][1];
            pr[row][o] = rstd * (S - mu * c12[o]) + c12[32 + o] + b2[o];
        }
    }
    __syncthreads();

    // -------- P3b: geometry, one row per thread --------
    if (tid < 8) {
        const int row = row8 + tid;
        float p[OUTC];
        #pragma unroll
        for (int oo = 0; oo < OUTC; ++oo) p[oo] = pr[tid][oo];

        float trans[3] = { p[0] * 10.f, p[1] * 10.f, p[2] * 10.f };
        float xv[3] = { p[3], p[4], p[5] };
        float yv[3] = { p[6], p[7], p[8] };
        float xn = sqrtf(xv[0]*xv[0] + xv[1]*xv[1] + xv[2]*xv[2]) + 1e-5f;
        xv[0] /= xn; xv[1] /= xn; xv[2] /= xn;
        float yn = sqrtf(yv[0]*yv[0] + yv[1]*yv[1] + yv[2]*yv[2]) + 1e-5f;
        yv[0] /= yn; yv[1] /= yn; yv[2] /= yn;

        float a0 = -xv[0], a1 = -xv[1], a2 = -xv[2];
        float inv = 1.f / sqrtf(a0*a0 + a1*a1 + a2*a2 + 1e-12f);
        float e0x = a0 * inv, e0y = a1 * inv, e0z = a2 * inv;
        float c = e0x*yv[0] + e0y*yv[1] + e0z*yv[2];
        float e1x = yv[0] - e0x * c, e1y = yv[1] - e0y * c, e1z = yv[2] - e0z * c;
        inv = 1.f / sqrtf(e1x*e1x + e1y*e1y + e1z*e1z + 1e-12f);
        e1x *= inv; e1y *= inv; e1z *= inv;
        float e2x = e0y*e1z - e0z*e1y;
        float e2y = e0z*e1x - e0x*e1z;
        float e2z = e0x*e1y - e0y*e1x;

        float Ru[3][3] = { { e0x, e1x, e2x },
                           { e0y, e1y, e2y },
                           { e0z, e1z, e2z } };
        float tu[3] = { trans[0], trans[1], trans[2] };
        if (amask[row] == 0) {
            Ru[0][0]=1.f; Ru[0][1]=0.f; Ru[0][2]=0.f;
            Ru[1][0]=0.f; Ru[1][1]=1.f; Ru[1][2]=0.f;
            Ru[2][0]=0.f; Ru[2][1]=0.f; Ru[2][2]=1.f;
            tu[0]=tu[1]=tu[2]=0.f;
        }

        const float* af = affine + (size_t)row * 12;
        float R0[3][3] = { { af[0], af[1], af[2] },
                           { af[3], af[4], af[5] },
                           { af[6], af[7], af[8] } };
        float t0[3] = { af[9], af[10], af[11] };

        float R[3][3], t[3];
        #pragma unroll
        for (int i = 0; i < 3; ++i) {
            #pragma unroll
            for (int j = 0; j < 3; ++j)
                R[i][j] = R0[i][0]*Ru[0][j] + R0[i][1]*Ru[1][j] + R0[i][2]*Ru[2][j];
            t[i] = R0[i][0]*tu[0] + R0[i][1]*tu[1] + R0[i][2]*tu[2] + t0[i];
        }

        float* oa = out + (size_t)row * 12;
        #pragma unroll
        for (int i = 0; i < 3; ++i) {
            #pragma unroll
            for (int j = 0; j < 3; ++j) oa[i*3 + j] = R[i][j];
            oa[9 + i] = t[i];
        }

        const float BB[3][3] = { { -0.525f, 1.363f, 0.f },
                                 {  0.f,    0.f,   0.f },
                                 {  1.526f, 0.f,   0.f } };
        float* op = out + AFF_SZ + (size_t)row * 9;
        #pragma unroll
        for (int a = 0; a < 3; ++a)
            #pragma unroll
            for (int i = 0; i < 3; ++i)
                op[a*3 + i] = R[i][0]*BB[a][0] + R[i][1]*BB[a][1] + R[i][2]*BB[a][2] + t[i];
    }
}

extern "C" void kernel_launch(void* const* d_in, const int* in_sizes, int n_in,
                              void* d_out, int out_size, void* d_ws, size_t ws_size,
                              hipStream_t stream) {
    const float* x      = (const float*)d_in[0];
    const float* affine = (const float*)d_in[1];
    const int*   amask  = (const int*)  d_in[2];
    const float* w1     = (const float*)d_in[3];
    const float* b1     = (const float*)d_in[4];
    const float* ln_g   = (const float*)d_in[5];
    const float* ln_b   = (const float*)d_in[6];
    const float* w2     = (const float*)d_in[7];
    const float* b2     = (const float*)d_in[8];
    float* out = (float*)d_out;

    unsigned char* ws = (unsigned char*)d_ws;
    unsigned short* Hb  = (unsigned short*)(ws);
    unsigned short* w1b = (unsigned short*)(ws + W1B_OFF);
    unsigned short* Wp  = (unsigned short*)(ws + WP_OFF);
    float*          c12 = (float*)(ws + C_OFF);

    setup_kernel<<<1152 + 24 + OUTC, 256, 0, stream>>>(w1, ln_g, ln_b, w2, w1b, Wp, c12);
    dim3 g1(MROWS / 64, NOUT / 128);   // 64 x 12 = 768 blocks
    gemm1_kernel<<<g1, 256, 0, stream>>>(x, w1b, b1, Hb);
    head_kernel<<<MROWS / 8, 256, 0, stream>>>(Hb, Wp, c12, b2, affine, amask, out);
}

// Round 7
// 195.360 us; speedup vs baseline: 1.0295x; 1.0295x over previous
//
#include <hip/hip_runtime.h>
#include <hip/hip_bf16.h>
#include <math.h>

typedef __bf16 bf16x8 __attribute__((ext_vector_type(8)));
typedef float floatx4 __attribute__((ext_vector_type(4)));

#define DK    1536   // inner dim D
#define MROWS 4096   // B*L
#define NOUT  1536   // first GEMM output dim
#define OUTC  23     // second GEMM output dim
#define AFF_SZ (MROWS * 12)

// ws layout (bytes): Hb @0 (12.58MB) | w1b @12582912 (4.72MB) | Wp @17301504
// (96KB, MFMA-B-fragment-permuted (g.*w2) bf16) | c12 @17399808 (64 floats)
#define W1B_OFF 12582912
#define WP_OFF  17301504
#define C_OFF   17399808

__device__ __forceinline__ unsigned int pkbf(float lo, float hi) {
    unsigned int a = __float_as_uint(lo) + 0x8000u;
    unsigned int b = __float_as_uint(hi) + 0x8000u;
    return (b & 0xffff0000u) | (a >> 16);
}
__device__ __forceinline__ unsigned short f2bf1(float v) {
    return (unsigned short)((__float_as_uint(v) + 0x8000u) >> 16);
}
__device__ __forceinline__ float bflo(unsigned int u) { return __uint_as_float(u << 16); }
__device__ __forceinline__ float bfhi(unsigned int u) { return __uint_as_float(u & 0xffff0000u); }

// ---------------------------------------------------------------------------
// Setup: w1 -> bf16; Wp = (ln_g .* w2) in MFMA B-fragment order:
//   chunk g in [0,6144): l=g&63, kbt=g>>6, kb=kbt>>1, tile=kbt&1,
//   o=tile*16+(l&15), k0=kb*32+(l>>4)*8 -> 8 bf16 at Wp[g*8].
// c1[o] = sum g*w2[o], c2[o] = sum lnb*w2[o].
// ---------------------------------------------------------------------------
__global__ __launch_bounds__(256)
void setup_kernel(const float* __restrict__ w1, const float* __restrict__ ln_g,
                  const float* __restrict__ ln_b, const float* __restrict__ w2,
                  unsigned short* __restrict__ w1b, unsigned short* __restrict__ wpb,
                  float* __restrict__ c12)
{
    const int b = blockIdx.x, tid = threadIdx.x;
    if (b < 1152) {                       // w1 convert: 1536*1536 = 1152*2048
        const int base = b * 2048 + tid * 8;
        float4 a = *(const float4*)(w1 + base);
        float4 c = *(const float4*)(w1 + base + 4);
        uint4 u;
        u.x = pkbf(a.x, a.y); u.y = pkbf(a.z, a.w);
        u.z = pkbf(c.x, c.y); u.w = pkbf(c.z, c.w);
        *(uint4*)(w1b + base) = u;
    } else if (b < 1176) {                // Wp permuted: 6144 chunks of 8
        const int g    = (b - 1152) * 256 + tid;   // 0..6143
        const int l    = g & 63;
        const int kbt  = g >> 6;                   // 0..95
        const int kb   = kbt >> 1, tile = kbt & 1;
        const int o    = tile * 16 + (l & 15);
        const int k0   = kb * 32 + (l >> 4) * 8;
        uint4 u = make_uint4(0, 0, 0, 0);
        if (o < OUTC) {
            float4 a  = *(const float4*)(w2 + (size_t)o * DK + k0);
            float4 c  = *(const float4*)(w2 + (size_t)o * DK + k0 + 4);
            float4 g0 = *(const float4*)(ln_g + k0);
            float4 g1 = *(const float4*)(ln_g + k0 + 4);
            u.x = pkbf(a.x * g0.x, a.y * g0.y);
            u.y = pkbf(a.z * g0.z, a.w * g0.w);
            u.z = pkbf(c.x * g1.x, c.y * g1.y);
            u.w = pkbf(c.z * g1.z, c.w * g1.w);
        }
        *(uint4*)(wpb + (size_t)g * 8) = u;
    } else {                              // c1/c2: one block per o
        const int o = b - 1176;
        float s1 = 0.f, s2 = 0.f;
        for (int d = tid; d < DK; d += 256) {
            float w = w2[(size_t)o * DK + d];
            s1 += ln_g[d] * w;
            s2 += ln_b[d] * w;
        }
        __shared__ float r1[4], r2[4];
        const int lane = tid & 63, wave = tid >> 6;
        #pragma unroll
        for (int off = 32; off > 0; off >>= 1) {
            s1 += __shfl_down(s1, off, 64);
            s2 += __shfl_down(s2, off, 64);
        }
        if (lane == 0) { r1[wave] = s1; r2[wave] = s2; }
        __syncthreads();
        if (tid == 0) {
            c12[o]      = r1[0] + r1[1] + r1[2] + r1[3];
            c12[32 + o] = r2[0] + r2[1] + r2[2] + r2[3];
        }
    }
}

// ---------------------------------------------------------------------------
// Kernel 1: Hb = bf16( gelu(x @ w1b^T + b1) )  [M=4096, N=1536, K=1536]
// BM=64, BN=128, BK=64 -> 768 blocks = 3/CU. 4 waves (2x2), wave 32x64.
// __launch_bounds__(256, 2) is REQUIRED: (256,4) and the unbounded default
// both target 8 waves/SIMD -> 56-60 VGPRs -> prefetch regs spill to scratch
// (~110 MB/dispatch HBM writebacks, rounds 5-6). (256,2) gives ~84-110 VGPRs,
// no spill (round 3: WRITE_SIZE 12.3 MB).
// ---------------------------------------------------------------------------
__global__ __launch_bounds__(256, 2)
void gemm1_kernel(const float* __restrict__ A, const unsigned short* __restrict__ Bw,
                  const float* __restrict__ b1, unsigned short* __restrict__ Hb)
{
    __shared__ __align__(16) unsigned short As[64][72];
    __shared__ __align__(16) unsigned short Bs[128][72];

    const int tid    = threadIdx.x;
    const int wave   = tid >> 6;
    const int lane   = tid & 63;
    const int wm     = (wave & 1) * 32;
    const int wn     = (wave >> 1) * 64;
    const int lane15 = lane & 15;
    const int quad   = lane >> 4;

    const int row0 = blockIdx.x * 64;
    const int col0 = blockIdx.y * 128;

    const int arow = tid >> 4;            // 0..15, +16*i
    const int ac4  = (tid & 15) << 2;     // 0..60 step 4
    const int brow = tid >> 3;            // 0..31, +32*i
    const int b8   = (tid & 7) << 3;      // 0..56 step 8

    const float*          Ap = A  + (size_t)(row0 + arow) * DK + ac4;
    const unsigned short* Bp = Bw + (size_t)(col0 + brow) * DK + b8;

    floatx4 acc[2][4] = {};
    float4 pa[4];
    uint4  pb[4];

    #pragma unroll
    for (int i = 0; i < 4; ++i) pa[i] = *(const float4*)(Ap + (size_t)(16 * i) * DK);
    #pragma unroll
    for (int i = 0; i < 4; ++i) pb[i] = *(const uint4*)(Bp + (size_t)(32 * i) * DK);

    #define STAGE_TILE()                                                        \
        do {                                                                    \
            _Pragma("unroll")                                                   \
            for (int i = 0; i < 4; ++i) {                                       \
                uint2 u = make_uint2(pkbf(pa[i].x, pa[i].y),                    \
                                     pkbf(pa[i].z, pa[i].w));                   \
                *(uint2*)(&As[arow + 16 * i][ac4]) = u;                         \
            }                                                                   \
            _Pragma("unroll")                                                   \
            for (int i = 0; i < 4; ++i)                                         \
                *(uint4*)(&Bs[brow + 32 * i][b8]) = pb[i];                      \
        } while (0)

    #define MFMA_TILE()                                                         \
        do {                                                                    \
            _Pragma("unroll")                                                   \
            for (int ks = 0; ks < 2; ++ks) {                                    \
                bf16x8 af[2], bfr[4];                                           \
                _Pragma("unroll")                                               \
                for (int mt = 0; mt < 2; ++mt)                                  \
                    af[mt] = *(const bf16x8*)(&As[wm + mt * 16 + lane15]        \
                                                [ks * 32 + quad * 8]);          \
                _Pragma("unroll")                                               \
                for (int nt = 0; nt < 4; ++nt)                                  \
                    bfr[nt] = *(const bf16x8*)(&Bs[wn + nt * 16 + lane15]       \
                                                 [ks * 32 + quad * 8]);         \
                _Pragma("unroll")                                               \
                for (int mt = 0; mt < 2; ++mt)                                  \
                    _Pragma("unroll")                                           \
                    for (int nt = 0; nt < 4; ++nt)                              \
                        acc[mt][nt] = __builtin_amdgcn_mfma_f32_16x16x32_bf16(  \
                            af[mt], bfr[nt], acc[mt][nt], 0, 0, 0);             \
            }                                                                   \
        } while (0)

    for (int k0 = 0; k0 < DK - 64; k0 += 64) {
        STAGE_TILE();
        #pragma unroll
        for (int i = 0; i < 4; ++i)
            pa[i] = *(const float4*)(Ap + (size_t)(16 * i) * DK + k0 + 64);
        #pragma unroll
        for (int i = 0; i < 4; ++i)
            pb[i] = *(const uint4*)(Bp + (size_t)(32 * i) * DK + k0 + 64);
        __syncthreads();
        MFMA_TILE();
        __syncthreads();
    }
    STAGE_TILE();
    __syncthreads();
    MFMA_TILE();

    #pragma unroll
    for (int mt = 0; mt < 2; ++mt)
        #pragma unroll
        for (int nt = 0; nt < 4; ++nt)
            #pragma unroll
            for (int r = 0; r < 4; ++r) {
                int row = row0 + wm + mt * 16 + quad * 4 + r;
                int col = col0 + wn + nt * 16 + lane15;
                float v = acc[mt][nt][r] + b1[col];
                v = 0.5f * v * (1.0f + erff(v * 0.70710678118654752f));
                Hb[(size_t)row * NOUT + col] = f2bf1(v);
            }
}

// ---------------------------------------------------------------------------
// Kernel 2: head. 8 rows/block (512 blocks).
// P1: load bf16 h -> LDS + LN stats. LN folded: p = rstd*(S - mu*c1) + c2 + b2.
// P2: S = h @ Wp^T via MFMA; Wp is pre-permuted to B-fragment order so each
//     wave's B-load is one contiguous coalesced 1KB transaction.
// P3: finish + geometry.
// ---------------------------------------------------------------------------
__global__ __launch_bounds__(256)
void head_kernel(const unsigned short* __restrict__ Hb, const unsigned short* __restrict__ Wp,
                 const float* __restrict__ c12, const float* __restrict__ b2,
                 const float* __restrict__ affine, const int* __restrict__ amask,
                 float* __restrict__ out)
{
    __shared__ __align__(16) unsigned short hb[8][DK];
    __shared__ float st[8][2];
    __shared__ float pred[4][16][32];
    __shared__ float pr[8][32];

    const int tid    = threadIdx.x;
    const int lane   = tid & 63;
    const int wave   = tid >> 6;
    const int lane15 = lane & 15;
    const int quad   = lane >> 4;
    const int row8   = blockIdx.x * 8;

    // -------- P1: load 2 rows per wave + stats --------
    #pragma unroll
    for (int rr = 0; rr < 2; ++rr) {
        const int r = wave * 2 + rr;
        const unsigned short* src = Hb + (size_t)(row8 + r) * DK;
        float s = 0.f, ss = 0.f;
        #pragma unroll
        for (int j = 0; j < 3; ++j) {
            const int e8 = lane + 64 * j;
            uint4 u = *(const uint4*)(src + e8 * 8);
            *(uint4*)(&hb[r][e8 * 8]) = u;
            float f0 = bflo(u.x), f1 = bfhi(u.x), f2 = bflo(u.y), f3 = bfhi(u.y);
            float f4 = bflo(u.z), f5 = bfhi(u.z), f6 = bflo(u.w), f7 = bfhi(u.w);
            s  += ((f0 + f1) + (f2 + f3)) + ((f4 + f5) + (f6 + f7));
            ss += ((f0*f0 + f1*f1) + (f2*f2 + f3*f3)) + ((f4*f4 + f5*f5) + (f6*f6 + f7*f7));
        }
        #pragma unroll
        for (int off = 32; off > 0; off >>= 1) {
            s  += __shfl_down(s, off, 64);
            ss += __shfl_down(ss, off, 64);
        }
        if (lane == 0) {
            float mu  = s * (1.f / DK);
            float var = ss * (1.f / DK) - mu * mu;
            st[r][0] = mu;
            st[r][1] = 1.f / sqrtf(var + 1e-5f);
        }
    }
    __syncthreads();

    // -------- P2: S = h @ Wp^T, wave = k-quarter, coalesced B loads --------
    {
        const int mrow = lane15 & 7;
        floatx4 a0 = {0.f, 0.f, 0.f, 0.f}, a1 = {0.f, 0.f, 0.f, 0.f};
        #pragma unroll
        for (int kk = 0; kk < 12; ++kk) {
            const int kb  = wave * 12 + kk;                 // global k-block
            const int kof = kb * 32 + quad * 8;
            bf16x8 afr = *(const bf16x8*)(&hb[mrow][kof]);
            bf16x8 b0  = *(const bf16x8*)(Wp + ((size_t)(kb * 2 + 0) * 64 + lane) * 8);
            bf16x8 b1f = *(const bf16x8*)(Wp + ((size_t)(kb * 2 + 1) * 64 + lane) * 8);
            a0 = __builtin_amdgcn_mfma_f32_16x16x32_bf16(afr, b0,  a0, 0, 0, 0);
            a1 = __builtin_amdgcn_mfma_f32_16x16x32_bf16(afr, b1f, a1, 0, 0, 0);
        }
        #pragma unroll
        for (int r2 = 0; r2 < 4; ++r2) {
            pred[wave][quad * 4 + r2][lane15]      = a0[r2];
            pred[wave][quad * 4 + r2][16 + lane15] = a1[r2];
        }
    }
    __syncthreads();

    // -------- P3a: finish p --------
    {
        const int row = tid >> 5;
        const int o   = tid & 31;
        if (o < OUTC) {
            float S = pred[0][row][o] + pred[1][row][o] + pred[2][row][o] + pred[3][row][o];
            float mu = st[row][0], rstd = st[row][1];
            pr[row][o] = rstd * (S - mu * c12[o]) + c12[32 + o] + b2[o];
        }
    }
    __syncthreads();

    // -------- P3b: geometry, one row per thread --------
    if (tid < 8) {
        const int row = row8 + tid;
        float p[OUTC];
        #pragma unroll
        for (int oo = 0; oo < OUTC; ++oo) p[oo] = pr[tid][oo];

        float trans[3] = { p[0] * 10.f, p[1] * 10.f, p[2] * 10.f };
        float xv[3] = { p[3], p[4], p[5] };
        float yv[3] = { p[6], p[7], p[8] };
        float xn = sqrtf(xv[0]*xv[0] + xv[1]*xv[1] + xv[2]*xv[2]) + 1e-5f;
        xv[0] /= xn; xv[1] /= xn; xv[2] /= xn;
        float yn = sqrtf(yv[0]*yv[0] + yv[1]*yv[1] + yv[2]*yv[2]) + 1e-5f;
        yv[0] /= yn; yv[1] /= yn; yv[2] /= yn;

        float a0 = -xv[0], a1 = -xv[1], a2 = -xv[2];
        float inv = 1.f / sqrtf(a0*a0 + a1*a1 + a2*a2 + 1e-12f);
        float e0x = a0 * inv, e0y = a1 * inv, e0z = a2 * inv;
        float c = e0x*yv[0] + e0y*yv[1] + e0z*yv[2];
        float e1x = yv[0] - e0x * c, e1y = yv[1] - e0y * c, e1z = yv[2] - e0z * c;
        inv = 1.f / sqrtf(e1x*e1x + e1y*e1y + e1z*e1z + 1e-12f);
        e1x *= inv; e1y *= inv; e1z *= inv;
        float e2x = e0y*e1z - e0z*e1y;
        float e2y = e0z*e1x - e0x*e1z;
        float e2z = e0x*e1y - e0y*e1x;

        float Ru[3][3] = { { e0x, e1x, e2x },
                           { e0y, e1y, e2y },
                           { e0z, e1z, e2z } };
        float tu[3] = { trans[0], trans[1], trans[2] };
        if (amask[row] == 0) {
            Ru[0][0]=1.f; Ru[0][1]=0.f; Ru[0][2]=0.f;
            Ru[1][0]=0.f; Ru[1][1]=1.f; Ru[1][2]=0.f;
            Ru[2][0]=0.f; Ru[2][1]=0.f; Ru[2][2]=1.f;
            tu[0]=tu[1]=tu[2]=0.f;
        }

        const float* af = affine + (size_t)row * 12;
        float R0[3][3] = { { af[0], af[1], af[2] },
                           { af[3], af[4], af[5] },
                           { af[6], af[7], af[8] } };
        float t0[3] = { af[9], af[10], af[11] };

        float R[3][3], t[3];
        #pragma unroll
        for (int i = 0; i < 3; ++i) {
            #pragma unroll
            for (int j = 0; j < 3; ++j)
                R[i][j] = R0[i][0]*Ru[0][j] + R0[i][1]*Ru[1][j] + R0[i][2]*Ru[2][j];
            t[i] = R0[i][0]*tu[0] + R0[i][1]*tu[1] + R0[i][2]*tu[2] + t0[i];
        }

        float* oa = out + (size_t)row * 12;
        #pragma unroll
        for (int i = 0; i < 3; ++i) {
            #pragma unroll
            for (int j = 0; j < 3; ++j) oa[i*3 + j] = R[i][j];
            oa[9 + i] = t[i];
        }

        const float BB[3][3] = { { -0.525f, 1.363f, 0.f },
                                 {  0.f,    0.f,   0.f },
                                 {  1.526f, 0.f,   0.f } };
        float* op = out + AFF_SZ + (size_t)row * 9;
        #pragma unroll
        for (int a = 0; a < 3; ++a)
            #pragma unroll
            for (int i = 0; i < 3; ++i)
                op[a*3 + i] = R[i][0]*BB[a][0] + R[i][1]*BB[a][1] + R[i][2]*BB[a][2] + t[i];
    }
}

extern "C" void kernel_launch(void* const* d_in, const int* in_sizes, int n_in,
                              void* d_out, int out_size, void* d_ws, size_t ws_size,
                              hipStream_t stream) {
    const float* x      = (const float*)d_in[0];
    const float* affine = (const float*)d_in[1];
    const int*   amask  = (const int*)  d_in[2];
    const float* w1     = (const float*)d_in[3];
    const float* b1     = (const float*)d_in[4];
    const float* ln_g   = (const float*)d_in[5];
    const float* ln_b   = (const float*)d_in[6];
    const float* w2     = (const float*)d_in[7];
    const float* b2     = (const float*)d_in[8];
    float* out = (float*)d_out;

    unsigned char* ws = (unsigned char*)d_ws;
    unsigned short* Hb  = (unsigned short*)(ws);
    unsigned short* w1b = (unsigned short*)(ws + W1B_OFF);
    unsigned short* Wp  = (unsigned short*)(ws + WP_OFF);
    float*          c12 = (float*)(ws + C_OFF);

    setup_kernel<<<1152 + 24 + OUTC, 256, 0, stream>>>(w1, ln_g, ln_b, w2, w1b, Wp, c12);
    dim3 g1(MROWS / 64, NOUT / 128);   // 64 x 12 = 768 blocks
    gemm1_kernel<<<g1, 256, 0, stream>>>(x, w1b, b1, Hb);
    head_kernel<<<MROWS / 8, 256, 0, stream>>>(Hb, Wp, c12, b2, affine, amask, out);
}